// Round 7
// baseline (1752.098 us; speedup 1.0000x reference)
//
#include <hip/hip_runtime.h>
#include <hip/hip_cooperative_groups.h>

namespace cg = cooperative_groups;

// ConvLSTM2D persistent cooperative kernel for MI355X (gfx950).
// B=8 T=16 H=W=256 C=3 F=36 K=5 stride4 VALID input conv; stride1 SAME recurrent.
// Ho=Wo=63, gates N=144 (permuted n' = fq*16 + g*4 + fr, f = fq*4+fr).
//
// Grid 256 blocks x 512 thr (8 waves = 2/SIMD), 1 block/CU, all 16 timesteps in
// one kernel with grid.sync between steps. Wave split 2M x 2N x 2K (K = chunk
// parity). Wh streamed as 30 K=32 chunks [144][40] fp16 through a 6-slot LDS
// ring (global_load_lds, 2 chunks/phase, 4-chunk prologue -> >=1 phase slack
// despite barrier vmcnt drains). x-conv uses K=16 MFMA with packed Wx.
// batch = bid%8 keeps each batch's h/c XCD-local (L2-resident).

typedef _Float16 f16;
typedef __attribute__((ext_vector_type(4))) _Float16 f16x4;
typedef __attribute__((ext_vector_type(8))) _Float16 f16x8;
typedef __attribute__((ext_vector_type(4))) float f32x4;

#define TPB 512

// ---- LDS layout (bytes) ----
// h_sh : ushort[6*2412]   @ 0       (28944)  6 haloed h rows, pitch 67*36
// x_sh : ushort[9*788]    @ 28944   (14184->14192) 9 input rows, pitch 788
// ring : ushort[6*5760]   @ 43136   (69120)  6 Wh chunk slots [144][40]
// w2_sh: ushort[5*144*20] @ 112256  (28800)  packed Wx, K=16 frags
// bp_sh: float[144]       @ 141056  (576)    permuted bias (persists)
// z_sh : float[128*148]   @ 0       (75776)  overlay on h+x+ring (all dead)
#define H_SH_OFF   0
#define X_SH_OFF   28944
#define RING_OFF   43136
#define W2_SH_OFF  112256
#define BP_OFF     141056
#define LDS_BYTES  141632
#define Z_SH_OFF   0

#define CHUNK_USH 5760   // 144*40 ushorts per Wh chunk
#define CHUNK_U4  720    // 11520B / 16

union Cv8 { ushort4 u4[2]; uint4 q; f16x8 h8; };
union Cv4 { ushort4 u; f16x4 h; };
union Cvh { f16 h; ushort u; };
union Cv2 { f16 h[2]; uint u; };

__device__ inline f16x8 ld8_lds(const ushort* p) {   // 8B-aligned (2x ds_read_b64)
  Cv8 c; c.u4[0] = *(const ushort4*)p; c.u4[1] = *(const ushort4*)(p + 4);
  return c.h8;
}
__device__ inline f16x8 ld16_lds(const ushort* p) {  // 16B-aligned (ds_read_b128)
  Cv8 c; c.q = *(const uint4*)p; return c.h8;
}
__device__ inline f16x4 ld4_lds(const ushort* p) {   // 8B-aligned (ds_read_b64)
  Cv4 c; c.u = *(const ushort4*)p; return c.h;
}
__device__ inline ushort f2us(float v) { Cvh c; c.h = (f16)v; return c.u; }

typedef const __attribute__((address_space(1))) uint guint;
typedef __attribute__((address_space(3))) uint luint;
__device__ inline void gload_lds16(const void* gp, void* lp) {
  __builtin_amdgcn_global_load_lds((guint*)gp, (luint*)lp, 16, 0, 0);
}

__device__ inline float tanh_fast(float x) {
  float e = __expf(2.f * x);                    // inf-safe: rcp(inf)=0 -> 1
  return 1.f - 2.f * __builtin_amdgcn_rcpf(e + 1.f);
}

// ---------------- weight prep ----------------
// whp: [ck=kh*6+cc6][n'(144)][40] fp16; k = cc6*32 + j, valid j<32 && k<180
// wxp: [kh2(5)][n'(144)][20] fp16; k2 = j, valid j<15 (=kw*3+cin)
// bperm: [n'] fp32
__global__ void prep_weights(const float* __restrict__ Wx, const float* __restrict__ Wh,
                             const float* __restrict__ bb,
                             ushort* __restrict__ whp, ushort* __restrict__ wxp,
                             float* __restrict__ bperm) {
  int i = blockIdx.x * 256 + threadIdx.x;
  if (i < 172800) {
    int j = i % 40; int rest = i / 40;
    int np = rest % 144; int ck = rest / 144;
    int kh = ck / 6, cc6 = ck - kh * 6;
    int k = cc6 * 32 + j;
    float v = 0.f;
    if (j < 32 && k < 180) {
      int kw = k / 36, c = k - kw * 36;
      int fq = np >> 4, g = (np >> 2) & 3, fr = np & 3;
      int n = g * 36 + fq * 4 + fr;
      v = Wh[(((kh * 5 + kw) * 36 + c) * 144) + n];
    }
    whp[i] = f2us(v);
  } else if (i < 187200) {
    int e = i - 172800;
    int j = e % 20; int rest = e / 20;
    int np = rest % 144; int kh2 = rest / 144;
    float v = 0.f;
    if (j < 15) {
      int kw = j / 3, cin = j - kw * 3;
      int fq = np >> 4, g = (np >> 2) & 3, fr = np & 3;
      int n = g * 36 + fq * 4 + fr;
      v = Wx[(((kh2 * 5 + kw) * 3 + cin) * 144) + n];
    }
    wxp[e] = f2us(v);
  } else if (i < 187344) {
    int np = i - 187200;
    int fq = np >> 4, g = (np >> 2) & 3, fr = np & 3;
    bperm[np] = bb[g * 36 + fq * 4 + fr];
  }
}

// ---------------- GEMM pieces ----------------
// MFMA layouts (m89/m91 family): A[m][k]: m=lane&15, k=lg*KG+j; B[k][n]: n=lane&15;
// D[m][n]: n=lane&15, m=lg*4+j.  (KG = K/4: 8 for K=32, 4 for K=16.)
template<int S, int FQ0, int K0, int K1>
__device__ void x_conv(f32x4 (&acc)[4][5], const ushort* x_sh, const ushort* w2,
                       int mh, int l16, int lg) {
#pragma unroll
  for (int kh2 = K0; kh2 < K1; ++kh2) {
    f16x4 a[4];
#pragma unroll
    for (int r = 0; r < 4; ++r)
      a[r] = ld4_lds(x_sh + (mh * 4 + kh2) * 788 + (r * 16 + l16) * 12 + lg * 4);
#pragma unroll
    for (int s = 0; s < S; ++s) {
      f16x4 bf = ld4_lds(w2 + (kh2 * 144 + (FQ0 + s) * 16 + l16) * 20 + lg * 4);
#pragma unroll
      for (int r = 0; r < 4; ++r)
        acc[r][s] = __builtin_amdgcn_mfma_f32_16x16x16f16(a[r], bf, acc[r][s], 0, 0, 0);
    }
  }
}

template<int S, int FQ0>
__device__ void h_phase(f32x4 (&acc)[4][5], const ushort* hrow, const ushort* wbuf,
                        int k0, int l16, int lg) {
  f16x8 a[4];
  // k>=180 pad is zero-weight; reads may run past hrow into staged-finite data.
#pragma unroll
  for (int r = 0; r < 4; ++r)
    a[r] = ld8_lds(hrow + (r * 16 + l16) * 36 + k0 + lg * 8);
#pragma unroll
  for (int s = 0; s < S; ++s) {
    f16x8 bf = ld16_lds(wbuf + ((FQ0 + s) * 16 + l16) * 40 + lg * 8);
#pragma unroll
    for (int r = 0; r < 4; ++r)
      acc[r][s] = __builtin_amdgcn_mfma_f32_16x16x32_f16(a[r], bf, acc[r][s], 0, 0, 0);
  }
}

template<int S, int FQ0, bool ADD>
__device__ void z_out(const f32x4 (&acc)[4][5], float* z_sh, int mh, int l16, int lg) {
#pragma unroll
  for (int r = 0; r < 4; ++r)
#pragma unroll
    for (int s = 0; s < S; ++s)
#pragma unroll
      for (int j = 0; j < 4; ++j) {
        float* p = &z_sh[(mh * 64 + r * 16 + lg * 4 + j) * 148 + (FQ0 + s) * 16 + l16];
        if (ADD) *p += acc[r][s][j]; else *p = acc[r][s][j];
      }
}

// ---------------- persistent cooperative kernel ----------------
__global__ __launch_bounds__(TPB, 2)
void convlstm_all(const float* __restrict__ x_all,
                  const ushort* __restrict__ whp, const ushort* __restrict__ wxp,
                  const float* __restrict__ bperm,
                  f16* __restrict__ hb0, f16* __restrict__ hb1,
                  float* __restrict__ c_st, float* __restrict__ out) {
  extern __shared__ char smem[];
  ushort* h_sh = (ushort*)(smem + H_SH_OFF);
  ushort* x_sh = (ushort*)(smem + X_SH_OFF);
  ushort* ring = (ushort*)(smem + RING_OFF);
  ushort* w2   = (ushort*)(smem + W2_SH_OFF);
  float*  bp_sh = (float*)(smem + BP_OFF);
  float*  z_sh  = (float*)(smem + Z_SH_OFF);

  cg::grid_group gg = cg::this_grid();

  const int tid = threadIdx.x;
  const int lane = tid & 63, w = tid >> 6;
  const int kq = w >> 2, mh = (w >> 1) & 1, nh = w & 1;
  const int l16 = lane & 15, lg = lane >> 4;
  const int bid = blockIdx.x;
  const int b = bid & 7;            // batch = XCD id (bid%8) -> h/c L2-local
  const int y0 = (bid >> 3) * 2;

  // one-time: Wx + bias -> LDS (drained at t=0's staging barrier)
  {
    const uint4* src = (const uint4*)wxp;
#pragma unroll
    for (int k = 0; k < 4; ++k) {
      int g = tid + k * 512;
      if (g < 1800) gload_lds16(src + g, (char*)w2 + (size_t)g * 16);
    }
    if (tid < 144) bp_sh[tid] = bperm[tid];
  }

#pragma unroll 1
  for (int t = 0; t < 16; ++t) {
    const f16* hp = (t & 1) ? hb1 : hb0;
    f16* hn = (t & 1) ? hb0 : hb1;
    const bool first = (t == 0), last = (t == 15);

    // ring prologue: chunks 0..3 -> slots 0..3
    if (!first) {
      const uint4* src = (const uint4*)whp;
#pragma unroll
      for (int k = 0; k < 6; ++k) {
        int g = tid + k * 512;
        if (g < 4 * CHUNK_U4) gload_lds16(src + g, (char*)ring + (size_t)g * 16);
      }
    }
    // stage x rows (fp32 -> fp16 via float4), zero 768..787 tail
    {
      const float* xr = x_all + (size_t)(b * 16 + t) * 196608;
      uint* xs = (uint*)x_sh;
#pragma unroll
      for (int k = 0; k < 4; ++k) {
        int g = tid + k * 512;
        if (g < 1728) {
          int row = g / 192, e = g - row * 192;
          int yi = y0 * 4 + row;
          float4 v = make_float4(0.f, 0.f, 0.f, 0.f);
          if (yi < 256) v = *(const float4*)(xr + yi * 768 + e * 4);
          Cv2 c0, c1;
          c0.h[0] = (f16)v.x; c0.h[1] = (f16)v.y;
          c1.h[0] = (f16)v.z; c1.h[1] = (f16)v.w;
          xs[row * 394 + e * 2]     = c0.u;
          xs[row * 394 + e * 2 + 1] = c1.u;
        }
      }
      if (tid < 90) {
        int row = tid / 10, u = 384 + (tid - (tid / 10) * 10);
        xs[row * 394 + u] = 0;
      }
    }
    // stage h rows (fp16, zero halo)
    if (!first) {
      const uint2* src = (const uint2*)hp;
      uint2* hs = (uint2*)h_sh;
#pragma unroll
      for (int k = 0; k < 8; ++k) {
        int g = tid + k * 512;
        if (g < 3618) {
          int row = g / 603, u2 = g - row * 603;
          int hy = y0 - 2 + row;
          uint2 val = make_uint2(0, 0);
          if (hy >= 0 && hy < 63 && u2 >= 18 && u2 < 585)
            val = src[(size_t)(b * 63 + hy) * 567 + (u2 - 18)];
          hs[g] = val;
        }
      }
    }
    __syncthreads();  // vmcnt drain: Wx(+t=0), ring 0-3, x/h ds_writes

    f32x4 acc[4][5];
#pragma unroll
    for (int r = 0; r < 4; ++r)
#pragma unroll
      for (int s = 0; s < 5; ++s) acc[r][s] = (f32x4)(0.f);

    // x-conv: kq=0 -> kh2 {0,1,2}; kq=1 -> {3,4}
    if (nh == 0) { if (kq == 0) x_conv<5, 0, 0, 3>(acc, x_sh, w2, mh, l16, lg);
                   else         x_conv<5, 0, 3, 5>(acc, x_sh, w2, mh, l16, lg); }
    else         { if (kq == 0) x_conv<4, 5, 0, 3>(acc, x_sh, w2, mh, l16, lg);
                   else         x_conv<4, 5, 3, 5>(acc, x_sh, w2, mh, l16, lg); }

    if (!first) {
      // 15 phases: phase (q,r3) computes chunks {6q+2r3, +1} (kq picks parity),
      // DMAs chunks {6q+2r3+4, +1}. Unroll-by-3 makes all slot/k0 static.
#pragma unroll 1
      for (int q = 0; q < 5; ++q) {
        const ushort* hrow = h_sh + (mh + q) * 2412;
#pragma unroll
        for (int r3 = 0; r3 < 3; ++r3) {
          int nc = 6 * q + 2 * r3 + 4;
          if (nc < 30) {
            const uint4* src = (const uint4*)whp + (size_t)nc * CHUNK_U4;
            char* dst = (char*)ring + ((2 * r3 + 4) % 6) * (CHUNK_USH * 2);
#pragma unroll
            for (int k = 0; k < 3; ++k) {
              int g = tid + k * 512;
              if (g < 2 * CHUNK_U4) gload_lds16(src + g, dst + (size_t)g * 16);
            }
          }
          const int cc6 = 2 * r3 + kq;                  // slot == cc6 == ck%6
          const ushort* wbuf = ring + cc6 * CHUNK_USH;
          if (nh == 0) h_phase<5, 0>(acc, hrow, wbuf, cc6 * 32, l16, lg);
          else         h_phase<4, 5>(acc, hrow, wbuf, cc6 * 32, l16, lg);
          __syncthreads();
        }
      }
    } else {
      __syncthreads();  // t=0: fence x_sh reads before z overlay
    }

    // z-reduce across K-groups (z overlays h/x/ring; w2/bp untouched)
    if (kq == 0) { if (nh == 0) z_out<5, 0, false>(acc, z_sh, mh, l16, lg);
                   else         z_out<4, 5, false>(acc, z_sh, mh, l16, lg); }
    __syncthreads();
    if (kq == 1) { if (nh == 0) z_out<5, 0, true>(acc, z_sh, mh, l16, lg);
                   else         z_out<4, 5, true>(acc, z_sh, mh, l16, lg); }
    __syncthreads();

    // gates + state update
#pragma unroll 1
    for (int it = 0; it < 9; ++it) {
      int u = tid + it * 512;                 // 9*512 == 128*36 exactly
      int x_sub = u / 36, f = u - x_sub * 36;
      int x = x_sub & 63, y = y0 + (x_sub >> 6);
      if (x < 63 && y < 63) {
        int cb = (f >> 2) * 16 + (f & 3);
        const float* zr = z_sh + x_sub * 148;
        float zi = zr[cb]      + bp_sh[cb];
        float zf = zr[cb + 4]  + bp_sh[cb + 4];
        float zc = zr[cb + 8]  + bp_sh[cb + 8];
        float zo = zr[cb + 12] + bp_sh[cb + 12];
        float gi = fminf(fmaxf(0.2f * zi + 0.5f, 0.f), 1.f);
        float gf = fminf(fmaxf(0.2f * zf + 0.5f, 0.f), 1.f);
        float go = fminf(fmaxf(0.2f * zo + 0.5f, 0.f), 1.f);
        float tc = tanh_fast(zc);
        size_t idx = (size_t)((b * 63 + y) * 63 + x) * 36 + f;
        float cold = first ? 0.f : c_st[idx];
        float cn = gf * cold + gi * tc;
        float hnv = go * tanh_fast(cn);
        c_st[idx] = cn;
        hn[idx] = (f16)hnv;
        if (last) out[(size_t)b * 142884 + ((y * 63 + x) * 36 + f)] = hnv;
      }
    }

    if (!last) { __threadfence(); gg.sync(); }
  }
}

// ---------------- host launcher ----------------
extern "C" void kernel_launch(void* const* d_in, const int* in_sizes, int n_in,
                              void* d_out, int out_size, void* d_ws, size_t ws_size,
                              hipStream_t stream) {
  (void)in_sizes; (void)n_in; (void)out_size; (void)ws_size;
  const float* states = (const float*)d_in[0];
  const float* Wx = (const float*)d_in[1];
  const float* Wh = (const float*)d_in[2];
  const float* bb = (const float*)d_in[3];
  float* out = (float*)d_out;
  char* ws = (char*)d_ws;

  ushort* whp   = (ushort*)(ws + 0);        // 345600 B
  ushort* wxp   = (ushort*)(ws + 345600);   // 28800 B
  float*  bperm = (float*)(ws + 374400);    // 576 B
  f16*    hb0   = (f16*)(ws + 374976);      // 2286144 B
  f16*    hb1   = (f16*)(ws + 2661120);     // 2286144 B
  float*  c_st  = (float*)(ws + 4947264);   // 4572288 B (total ~9.5 MB)

  (void)hipFuncSetAttribute((const void*)convlstm_all,
                      hipFuncAttributeMaxDynamicSharedMemorySize, LDS_BYTES);

  prep_weights<<<732, 256, 0, stream>>>(Wx, Wh, bb, whp, wxp, bperm);

  const float* xa = states;
  void* args[] = { (void*)&xa, (void*)&whp, (void*)&wxp, (void*)&bperm,
                   (void*)&hb0, (void*)&hb1, (void*)&c_st, (void*)&out };
  (void)hipLaunchCooperativeKernel((void*)convlstm_all, dim3(256), dim3(TPB),
                             args, LDS_BYTES, stream);
}